// Round 5
// baseline (173.459 us; speedup 1.0000x reference)
//
#include <hip/hip_runtime.h>
#include <hip/hip_bf16.h>

typedef float f32x4 __attribute__((ext_vector_type(4)));
typedef float f32x16 __attribute__((ext_vector_type(16)));
typedef short bf16x8 __attribute__((ext_vector_type(8)));

#define NSEQ 2048
#define CDIM 1024
#define NHEAD 16
#define HDIM 64
#define MROWS 4096
// scale(1/8) * log2(e) folded into Q at projection epilogue
#define QSCALE 0.18033688011f
// defer-max threshold: 8 / ln(2) (P bounded by e^8)
#define DEFER_THR 11.5416f

__device__ __forceinline__ unsigned short f2bf(float f) {
    unsigned int u = __builtin_bit_cast(unsigned int, f);
    u += 0x7FFFu + ((u >> 16) & 1u);
    return (unsigned short)(u >> 16);
}

__device__ __forceinline__ unsigned pkbf(float lo, float hi_) {
    unsigned r;
    asm("v_cvt_pk_bf16_f32 %0, %1, %2" : "=v"(r) : "v"(lo), "v"(hi_));
    return r;
}

__device__ __forceinline__ void gload16(const void* g, void* l) {
    __builtin_amdgcn_global_load_lds(
        (const __attribute__((address_space(1))) unsigned int*)g,
        (__attribute__((address_space(3))) unsigned int*)l, 16, 0, 0);
}

// ---------------- f32 -> bf16 for the three weight matrices only ---------
__global__ __launch_bounds__(256) void cvt3_kernel(
    const float* __restrict__ wq, const float* __restrict__ wk, const float* __restrict__ wv,
    unsigned short* __restrict__ dwq, unsigned short* __restrict__ dwk,
    unsigned short* __restrict__ dwv)
{
    int b = blockIdx.x;
    const float* s; unsigned short* d; int base;
    if (b < 1024)      { s = wq; d = dwq; base = b; }
    else if (b < 2048) { s = wk; d = dwk; base = b - 1024; }
    else               { s = wv; d = dwv; base = b - 2048; }
    int i = (base * 256 + threadIdx.x) * 4;
    float4 t4 = *reinterpret_cast<const float4*>(s + i);
    ushort4 o;
    o.x = f2bf(t4.x); o.y = f2bf(t4.y); o.z = f2bf(t4.z); o.w = f2bf(t4.w);
    *reinterpret_cast<ushort4*>(d + i) = o;
}

// ---------------- fused projection GEMM + bias + RoPE -------------------
// A (X, f32) reg-staged with fused cvt; B (W, bf16) via global_load_lds.
// Both LDS tiles [128][64] bf16 with XOR swizzle (byte ^= (row&7)<<4).
__global__ __launch_bounds__(256) void gemm_rope_kernel(
    const float* __restrict__ Xq, const float* __restrict__ Xk,
    const float* __restrict__ Xv,
    const unsigned short* __restrict__ Wqb, const unsigned short* __restrict__ Wkb,
    const unsigned short* __restrict__ Wvb,
    const float* __restrict__ bq, const float* __restrict__ bk, const float* __restrict__ bv,
    const float* __restrict__ qcos, const float* __restrict__ qsin,
    const float* __restrict__ kcos, const float* __restrict__ ksin,
    unsigned short* __restrict__ Qh, unsigned short* __restrict__ Kh,
    unsigned short* __restrict__ VT)
{
    __shared__ unsigned char Asm[16384];   // [128 m][128B k]
    __shared__ unsigned char Bsm[16384];   // [128 j][128B k]

    const int tid  = threadIdx.x;
    const int wave = tid >> 6;
    const int lane = tid & 63;
    const int lr   = lane & 15;
    const int lg   = lane >> 4;
    const int wm   = wave >> 1;
    const int wn   = wave & 1;
    const int m0   = blockIdx.y * 128;
    const int j0   = blockIdx.x * 128;
    const int z    = blockIdx.z;

    const float* X = (z == 0) ? Xq : (z == 1) ? Xk : Xv;
    const unsigned short* W = (z == 0) ? Wqb : (z == 1) ? Wkb : Wvb;
    const float* bias = (z == 0) ? bq : (z == 1) ? bk : bv;
    const float* cosb = (z == 0) ? qcos : kcos;
    const float* sinb = (z == 0) ? qsin : ksin;

    // B staging (gload_lds): pre-swizzled source
    const int sr7 = lane >> 3;
    const int scb = ((lane & 7) * 16) ^ (sr7 << 4);
    // A staging (reg+cvt): slot s = i*256+tid -> row s>>3, slotcol tid&7
    const int asc   = tid & 7;                       // 16B slot in row
    const int aswz  = (asc * 16) ^ (((tid >> 3) & 7) << 4);
    // fragment read swizzle
    const int fsw = (lr & 7) << 4;

    f32x4 acc[4][4];
    const f32x4 zero4 = {0.f, 0.f, 0.f, 0.f};
    #pragma unroll
    for (int a = 0; a < 4; a++)
        #pragma unroll
        for (int b = 0; b < 4; b++) acc[a][b] = zero4;

    for (int k0 = 0; k0 < CDIM; k0 += 64) {
        __syncthreads();
        // B: async global->LDS (issue first, latency hides under A VALU work)
        #pragma unroll
        for (int i = 0; i < 4; i++) {
            const int ch  = wave * 4 + i;
            const int row = ch * 8 + sr7;
            gload16((const char*)W + ((size_t)(j0 + row) * CDIM + k0) * 2 + scb,
                    Bsm + ch * 1024);
        }
        // A: f32 load -> cvt_pk -> swizzled ds_write
        #pragma unroll
        for (int i = 0; i < 4; i++) {
            const int row = (i * 256 + tid) >> 3;
            const float4* px = reinterpret_cast<const float4*>(
                X + (size_t)(m0 + row) * CDIM + k0 + asc * 8);
            float4 a = px[0], b = px[1];
            uint4 w;
            w.x = pkbf(a.x, a.y); w.y = pkbf(a.z, a.w);
            w.z = pkbf(b.x, b.y); w.w = pkbf(b.z, b.w);
            *reinterpret_cast<uint4*>(&Asm[row * 128 + aswz]) = w;
        }
        __syncthreads();
        #pragma unroll
        for (int ks = 0; ks < 2; ks++) {
            bf16x8 af[4], bfm[4];
            #pragma unroll
            for (int mi = 0; mi < 4; mi++)
                af[mi] = *reinterpret_cast<const bf16x8*>(
                    &Asm[(wm * 64 + 16 * mi + lr) * 128 + ((ks * 64 + lg * 16) ^ fsw)]);
            #pragma unroll
            for (int ni = 0; ni < 4; ni++)
                bfm[ni] = *reinterpret_cast<const bf16x8*>(
                    &Bsm[(wn * 64 + 16 * ni + lr) * 128 + ((ks * 64 + lg * 16) ^ fsw)]);
            #pragma unroll
            for (int mi = 0; mi < 4; mi++)
                #pragma unroll
                for (int ni = 0; ni < 4; ni++)
                    acc[mi][ni] = __builtin_amdgcn_mfma_f32_16x16x32_bf16(
                        af[mi], bfm[ni], acc[mi][ni], 0, 0, 0);
        }
    }

    #pragma unroll
    for (int mi = 0; mi < 4; mi++) {
        const int mbase = m0 + wm * 64 + 16 * mi + 4 * lg;
        #pragma unroll
        for (int ni = 0; ni < 4; ni++) {
            const int j  = j0 + wn * 64 + 16 * ni + lr;
            const float bj = bias[j];
            if (z == 2) {
                const int b = mbase >> 11, n = mbase & 2047;
                const int h = j >> 6, d = j & 63;
                ushort4 pk;
                pk.x = f2bf(acc[mi][ni][0] + bj);
                pk.y = f2bf(acc[mi][ni][1] + bj);
                pk.z = f2bf(acc[mi][ni][2] + bj);
                pk.w = f2bf(acc[mi][ni][3] + bj);
                *reinterpret_cast<ushort4*>(VT + ((size_t)((b * NHEAD + h) * HDIM + d) << 11) + n) = pk;
            } else {
                unsigned short* Out = (z == 0) ? Qh : Kh;
                const float scl = (z == 0) ? QSCALE : 1.0f;
                const int hi = (j & 63) >> 1;
                const float sg = (j & 1) ? 1.f : -1.f;
                float vv[4], pp[4];
                #pragma unroll
                for (int r = 0; r < 4; r++) vv[r] = acc[mi][ni][r] + bj;
                #pragma unroll
                for (int r = 0; r < 4; r++) pp[r] = __shfl_xor(vv[r], 1);
                #pragma unroll
                for (int r = 0; r < 4; r++) {
                    const int m = mbase + r;
                    const int b = m >> 11, n = m & 2047;
                    const float c = cosb[n * 32 + hi];
                    const float s = sinb[n * 32 + hi];
                    const float ov = fmaf(vv[r], c, pp[r] * (sg * s)) * scl;
                    Out[((size_t)((b * NHEAD + (j >> 6)) * NSEQ + n) << 6) + (j & 63)] = f2bf(ov);
                }
            }
        }
    }
}

// ---------------- flash attention: T14 async-STAGE split ----------------
// grid (16, 32). 4 waves x 32 q-rows. KV tiles of 64, double-buffered.
// Loads for tile t+1 issued (to regs) BEFORE tile t's compute; ds_write
// after PV; raw s_barrier + lgkmcnt(0) only — no vmcnt drain in the loop.
__global__ __launch_bounds__(256, 2) void attn_kernel(
    const unsigned short* __restrict__ Qh, const unsigned short* __restrict__ Kh,
    const unsigned short* __restrict__ VT, float* __restrict__ out)
{
    __shared__ unsigned char Ksm[2][8192];   // [64 keys][128B d], swizzled
    __shared__ unsigned char Vsm[2][8192];   // [64 d][128B keys], swizzled

    const int tid  = threadIdx.x;
    const int wave = tid >> 6;
    const int lane = tid & 63;
    const int c    = lane & 31;
    const int hi   = lane >> 5;
    const int bh   = blockIdx.y;
    const int q0w  = blockIdx.x * 128 + wave * 32;
    const int sw   = (c & 7) << 4;           // read-side XOR swizzle

    const unsigned short* Qb = Qh + (size_t)bh * NSEQ * HDIM;
    const char* Kb = (const char*)(Kh + (size_t)bh * NSEQ * HDIM);
    const char* Vb = (const char*)(VT + (size_t)bh * HDIM * NSEQ);

    // Q as B-operand: lane holds Q[d = 16s+8hi+j][q = q0w+c] (pre-scaled)
    bf16x8 qf[4];
    #pragma unroll
    for (int s = 0; s < 4; s++)
        qf[s] = *reinterpret_cast<const bf16x8*>(
            Qb + (size_t)(q0w + c) * HDIM + s * 16 + hi * 8);

    const f32x16 z16 = {0,0,0,0,0,0,0,0,0,0,0,0,0,0,0,0};
    f32x16 o0 = z16, o1 = z16;
    float mrun = -1e30f, lrun = 0.f;

    // staging: slot s = i*256+tid -> row s>>3, 16B slot tid&7
    const int sc16 = (tid & 7) * 16;
    const int swsl = sc16 ^ (((tid >> 3) & 7) << 4);

    uint4 kr[2], vr[2];
    auto issue = [&](int n0) {
        #pragma unroll
        for (int i = 0; i < 2; ++i) {
            const int row = (i * 256 + tid) >> 3;
            kr[i] = *reinterpret_cast<const uint4*>(Kb + (size_t)(n0 + row) * 128 + sc16);
            vr[i] = *reinterpret_cast<const uint4*>(Vb + (size_t)row * (NSEQ * 2) +
                                                    (size_t)n0 * 2 + sc16);
        }
    };
    auto write = [&](int buf) {
        #pragma unroll
        for (int i = 0; i < 2; ++i) {
            const int row = (i * 256 + tid) >> 3;
            *reinterpret_cast<uint4*>(&Ksm[buf][row * 128 + swsl]) = kr[i];
            *reinterpret_cast<uint4*>(&Vsm[buf][row * 128 + swsl]) = vr[i];
        }
    };

    issue(0);
    write(0);            // compiler inserts the vmcnt waits for kr/vr deps
    issue(64);           // tile 1 in flight across the barrier
    asm volatile("s_waitcnt lgkmcnt(0)\n\ts_barrier" ::: "memory");

    for (int t = 0; t < 32; ++t) {
        const int cur = t & 1;

        // S^T tiles: s0 = keys 0..31, s1 = keys 32..63 (cols = q)
        f32x16 s0 = z16, s1 = z16;
        __builtin_amdgcn_s_setprio(1);
        #pragma unroll
        for (int s = 0; s < 4; s++) {
            const int cb = (32 * s + 16 * hi) ^ sw;
            bf16x8 kf0 = *reinterpret_cast<const bf16x8*>(&Ksm[cur][c * 128 + cb]);
            bf16x8 kf1 = *reinterpret_cast<const bf16x8*>(&Ksm[cur][(32 + c) * 128 + cb]);
            s0 = __builtin_amdgcn_mfma_f32_32x32x16_bf16(kf0, qf[s], s0, 0, 0, 0);
            s1 = __builtin_amdgcn_mfma_f32_32x32x16_bf16(kf1, qf[s], s1, 0, 0, 0);
        }
        __builtin_amdgcn_s_setprio(0);

        // row max: 31 in-lane + 1 partner exchange (lane^32 holds other keys)
        float tmx[8];
        #pragma unroll
        for (int i = 0; i < 8; i++)
            tmx[i] = fmaxf(fmaxf(s0[2 * i], s0[2 * i + 1]),
                           fmaxf(s1[2 * i], s1[2 * i + 1]));
        float tm = fmaxf(fmaxf(fmaxf(tmx[0], tmx[1]), fmaxf(tmx[2], tmx[3])),
                         fmaxf(fmaxf(tmx[4], tmx[5]), fmaxf(tmx[6], tmx[7])));
        tm = fmaxf(tm, __shfl_xor(tm, 32));

        // defer-max: rescale only when a row max grew past threshold
        if (!__all(tm - mrun <= DEFER_THR)) {
            const float mnew  = fmaxf(mrun, tm);
            const float alpha = exp2f(mrun - mnew);
            mrun = mnew;
            lrun *= alpha;
            #pragma unroll
            for (int r = 0; r < 16; r++) {
                const float ar = __shfl(alpha, (r & 3) + 8 * (r >> 2) + 4 * hi);
                o0[r] *= ar;
                o1[r] *= ar;
            }
        }

        // P = exp2(S - m), row sum
        #pragma unroll
        for (int r = 0; r < 16; r++) s0[r] = exp2f(s0[r] - mrun);
        #pragma unroll
        for (int r = 0; r < 16; r++) s1[r] = exp2f(s1[r] - mrun);
        float rsx[8];
        #pragma unroll
        for (int i = 0; i < 8; i++)
            rsx[i] = (s0[2 * i] + s0[2 * i + 1]) + (s1[2 * i] + s1[2 * i + 1]);
        float rs = ((rsx[0] + rsx[1]) + (rsx[2] + rsx[3])) +
                   ((rsx[4] + rsx[5]) + (rsx[6] + rsx[7]));
        rs += __shfl_xor(rs, 32);
        lrun += rs;

        // P -> A-fragments in-register: cvt_pk pairs + permlane32_swap
        unsigned pw[4][4];
        #pragma unroll
        for (int u = 0; u < 4; u++) {
            const f32x16& sv = (u < 2) ? s0 : s1;
            const int b = (u & 1) * 8;
            unsigned x0 = pkbf(sv[b + 0], sv[b + 1]);
            unsigned y0 = pkbf(sv[b + 4], sv[b + 5]);
            asm("v_permlane32_swap_b32 %0, %1" : "+v"(x0), "+v"(y0));
            unsigned x1 = pkbf(sv[b + 2], sv[b + 3]);
            unsigned y1 = pkbf(sv[b + 6], sv[b + 7]);
            asm("v_permlane32_swap_b32 %0, %1" : "+v"(x1), "+v"(y1));
            pw[u][0] = x0; pw[u][1] = x1; pw[u][2] = y0; pw[u][3] = y1;
        }

        // O += P V  (o0: d 0..31, o1: d 32..63)
        __builtin_amdgcn_s_setprio(1);
        #pragma unroll
        for (int u = 0; u < 4; u++) {
            uint4 w;
            w.x = pw[u][0]; w.y = pw[u][1]; w.z = pw[u][2]; w.w = pw[u][3];
            bf16x8 pa = __builtin_bit_cast(bf16x8, w);
            const int cb = (32 * u + 16 * hi) ^ sw;
            bf16x8 vf0 = *reinterpret_cast<const bf16x8*>(&Vsm[cur][c * 128 + cb]);
            bf16x8 vf1 = *reinterpret_cast<const bf16x8*>(&Vsm[cur][(32 + c) * 128 + cb]);
            o0 = __builtin_amdgcn_mfma_f32_32x32x16_bf16(pa, vf0, o0, 0, 0, 0);
            o1 = __builtin_amdgcn_mfma_f32_32x32x16_bf16(pa, vf1, o1, 0, 0, 0);
        }
        __builtin_amdgcn_s_setprio(0);

        if (t < 31) {
            write(cur ^ 1);               // tile t+1 regs -> LDS (vmcnt by compiler)
            if (t < 30) issue((t + 2) * 64);   // tile t+2 in flight across barrier
            asm volatile("s_waitcnt lgkmcnt(0)\n\ts_barrier" ::: "memory");
        }
    }

    // epilogue: normalize rows, write [B,N,C] f32
    const int b = bh >> 4, h = bh & 15;
    #pragma unroll
    for (int r = 0; r < 16; r++) {
        const int qrow = (r & 3) + 8 * (r >> 2) + 4 * hi;
        const float li  = __shfl(lrun, qrow);
        const float inv = 1.0f / li;
        const int n = q0w + qrow;
        float* op = out + ((size_t)(b * NSEQ + n) << 10) + h * HDIM + c;
        op[0]  = o0[r] * inv;
        op[32] = o1[r] * inv;
    }
}

extern "C" void kernel_launch(void* const* d_in, const int* in_sizes, int n_in,
                              void* d_out, int out_size, void* d_ws, size_t ws_size,
                              hipStream_t stream) {
    const float* q    = (const float*)d_in[0];
    const float* k    = (const float*)d_in[1];
    const float* v    = (const float*)d_in[2];
    const float* qcos = (const float*)d_in[3];
    const float* qsin = (const float*)d_in[4];
    const float* kcos = (const float*)d_in[5];
    const float* ksin = (const float*)d_in[6];
    const float* Wq   = (const float*)d_in[7];
    const float* bq   = (const float*)d_in[8];
    const float* Wk   = (const float*)d_in[9];
    const float* bk   = (const float*)d_in[10];
    const float* Wv   = (const float*)d_in[11];
    const float* bv   = (const float*)d_in[12];
    float* out = (float*)d_out;

    unsigned short* Wqb = (unsigned short*)d_ws;
    unsigned short* Wkb = Wqb + (size_t)CDIM * CDIM;
    unsigned short* Wvb = Wkb + (size_t)CDIM * CDIM;
    unsigned short* Qhb = Wvb + (size_t)CDIM * CDIM;
    unsigned short* Khb = Qhb + (size_t)MROWS * CDIM;
    unsigned short* VTb = Khb + (size_t)MROWS * CDIM;

    cvt3_kernel<<<3072, 256, 0, stream>>>(Wq, Wk, Wv, Wqb, Wkb, Wvb);

    dim3 gg(CDIM / 128, MROWS / 128, 3);
    gemm_rope_kernel<<<gg, 256, 0, stream>>>(q, k, v, Wqb, Wkb, Wvb,
                                             bq, bk, bv, qcos, qsin, kcos, ksin,
                                             Qhb, Khb, VTb);

    attn_kernel<<<dim3(NSEQ / 128, 2 * NHEAD), 256, 0, stream>>>(Qhb, Khb, VTb, out);
}

// Round 6
// 143.595 us; speedup vs baseline: 1.2080x; 1.2080x over previous
//
#include <hip/hip_runtime.h>
#include <hip/hip_bf16.h>

typedef float f32x4 __attribute__((ext_vector_type(4)));
typedef float f32x16 __attribute__((ext_vector_type(16)));
typedef short bf16x8 __attribute__((ext_vector_type(8)));

#define NSEQ 2048
#define CDIM 1024
#define NHEAD 16
#define HDIM 64
#define MROWS 4096
// scale(1/8) * log2(e) folded into Q at projection epilogue
#define QSCALE 0.18033688011f
// defer-max threshold: 8 / ln(2) (P bounded by e^8)
#define DEFER_THR 11.5416f

__device__ __forceinline__ unsigned short f2bf(float f) {
    unsigned int u = __builtin_bit_cast(unsigned int, f);
    u += 0x7FFFu + ((u >> 16) & 1u);
    return (unsigned short)(u >> 16);
}

__device__ __forceinline__ unsigned pkbf(float lo, float hi_) {
    unsigned r;
    asm("v_cvt_pk_bf16_f32 %0, %1, %2" : "=v"(r) : "v"(lo), "v"(hi_));
    return r;
}

__device__ __forceinline__ void gload16(const void* g, void* l) {
    __builtin_amdgcn_global_load_lds(
        (const __attribute__((address_space(1))) unsigned int*)g,
        (__attribute__((address_space(3))) unsigned int*)l, 16, 0, 0);
}

// ---------------- all f32->bf16 conversions in ONE launch ----------------
__global__ __launch_bounds__(256) void cvt6_kernel(
    const float* __restrict__ q, const float* __restrict__ k, const float* __restrict__ v,
    const float* __restrict__ wq, const float* __restrict__ wk, const float* __restrict__ wv,
    unsigned short* __restrict__ dq, unsigned short* __restrict__ dk, unsigned short* __restrict__ dv,
    unsigned short* __restrict__ dwq, unsigned short* __restrict__ dwk, unsigned short* __restrict__ dwv)
{
    int b = blockIdx.x;
    const float* s; unsigned short* d; int base;
    if (b < 4096)       { s = q;  d = dq;  base = b; }
    else if (b < 8192)  { s = k;  d = dk;  base = b - 4096; }
    else if (b < 12288) { s = v;  d = dv;  base = b - 8192; }
    else if (b < 13312) { s = wq; d = dwq; base = b - 12288; }
    else if (b < 14336) { s = wk; d = dwk; base = b - 13312; }
    else                { s = wv; d = dwv; base = b - 14336; }
    int i = (base * 256 + threadIdx.x) * 4;
    float4 t4 = *reinterpret_cast<const float4*>(s + i);
    ushort4 o;
    o.x = f2bf(t4.x); o.y = f2bf(t4.y); o.z = f2bf(t4.z); o.w = f2bf(t4.w);
    *reinterpret_cast<ushort4*>(d + i) = o;
}

// ---------------- fused projection GEMM + bias + RoPE -------------------
// round-3 structure: padded LDS [128][72], bf16x8 VALU staging (best measured)
__global__ __launch_bounds__(256) void gemm_rope_kernel(
    const unsigned short* __restrict__ Xq, const unsigned short* __restrict__ Xk,
    const unsigned short* __restrict__ Xv,
    const unsigned short* __restrict__ Wqb, const unsigned short* __restrict__ Wkb,
    const unsigned short* __restrict__ Wvb,
    const float* __restrict__ bq, const float* __restrict__ bk, const float* __restrict__ bv,
    const float* __restrict__ qcos, const float* __restrict__ qsin,
    const float* __restrict__ kcos, const float* __restrict__ ksin,
    unsigned short* __restrict__ Qh, unsigned short* __restrict__ Kh,
    unsigned short* __restrict__ VT)
{
    __shared__ unsigned short Al[128][72];
    __shared__ unsigned short Bl[128][72];

    const int tid  = threadIdx.x;
    const int wave = tid >> 6;
    const int lane = tid & 63;
    const int lr   = lane & 15;
    const int lg   = lane >> 4;
    const int lk   = lg * 8;
    const int wm   = wave >> 1;
    const int wn   = wave & 1;
    const int m0   = blockIdx.y * 128;
    const int j0   = blockIdx.x * 128;
    const int z    = blockIdx.z;

    const unsigned short* X = (z == 0) ? Xq : (z == 1) ? Xk : Xv;
    const unsigned short* W = (z == 0) ? Wqb : (z == 1) ? Wkb : Wvb;
    const float* bias = (z == 0) ? bq : (z == 1) ? bk : bv;
    const float* cosb = (z == 0) ? qcos : kcos;
    const float* sinb = (z == 0) ? qsin : ksin;

    f32x4 acc[4][4];
    const f32x4 zero4 = {0.f, 0.f, 0.f, 0.f};
    #pragma unroll
    for (int a = 0; a < 4; a++)
        #pragma unroll
        for (int b = 0; b < 4; b++) acc[a][b] = zero4;

    for (int k0 = 0; k0 < CDIM; k0 += 64) {
        __syncthreads();
        #pragma unroll
        for (int it = 0; it < 4; it++) {
            int c = tid + it * 256;
            int row = c >> 3, col = (c & 7) << 3;
            *reinterpret_cast<bf16x8*>(&Al[row][col]) =
                *reinterpret_cast<const bf16x8*>(X + (size_t)(m0 + row) * CDIM + k0 + col);
            *reinterpret_cast<bf16x8*>(&Bl[row][col]) =
                *reinterpret_cast<const bf16x8*>(W + (size_t)(j0 + row) * CDIM + k0 + col);
        }
        __syncthreads();
        #pragma unroll
        for (int ks = 0; ks < 2; ks++) {
            bf16x8 af[4], bfm[4];
            #pragma unroll
            for (int mi = 0; mi < 4; mi++)
                af[mi] = *reinterpret_cast<const bf16x8*>(&Al[wm * 64 + 16 * mi + lr][ks * 32 + lk]);
            #pragma unroll
            for (int ni = 0; ni < 4; ni++)
                bfm[ni] = *reinterpret_cast<const bf16x8*>(&Bl[wn * 64 + 16 * ni + lr][ks * 32 + lk]);
            #pragma unroll
            for (int mi = 0; mi < 4; mi++)
                #pragma unroll
                for (int ni = 0; ni < 4; ni++)
                    acc[mi][ni] = __builtin_amdgcn_mfma_f32_16x16x32_bf16(
                        af[mi], bfm[ni], acc[mi][ni], 0, 0, 0);
        }
    }

    #pragma unroll
    for (int mi = 0; mi < 4; mi++) {
        const int mbase = m0 + wm * 64 + 16 * mi + 4 * lg;
        #pragma unroll
        for (int ni = 0; ni < 4; ni++) {
            const int j  = j0 + wn * 64 + 16 * ni + lr;
            const float bj = bias[j];
            if (z == 2) {
                const int b = mbase >> 11, n = mbase & 2047;
                const int h = j >> 6, d = j & 63;
                ushort4 pk;
                pk.x = f2bf(acc[mi][ni][0] + bj);
                pk.y = f2bf(acc[mi][ni][1] + bj);
                pk.z = f2bf(acc[mi][ni][2] + bj);
                pk.w = f2bf(acc[mi][ni][3] + bj);
                *reinterpret_cast<ushort4*>(VT + ((size_t)((b * NHEAD + h) * HDIM + d) << 11) + n) = pk;
            } else {
                unsigned short* Out = (z == 0) ? Qh : Kh;
                const float scl = (z == 0) ? QSCALE : 1.0f;
                const int hi = (j & 63) >> 1;
                const float sg = (j & 1) ? 1.f : -1.f;
                float vv[4], pp[4];
                #pragma unroll
                for (int r = 0; r < 4; r++) vv[r] = acc[mi][ni][r] + bj;
                #pragma unroll
                for (int r = 0; r < 4; r++) pp[r] = __shfl_xor(vv[r], 1);
                #pragma unroll
                for (int r = 0; r < 4; r++) {
                    const int m = mbase + r;
                    const int b = m >> 11, n = m & 2047;
                    const float c = cosb[n * 32 + hi];
                    const float s = sinb[n * 32 + hi];
                    const float ov = fmaf(vv[r], c, pp[r] * (sg * s)) * scl;
                    Out[((size_t)((b * NHEAD + (j >> 6)) * NSEQ + n) << 6) + (j & 63)] = f2bf(ov);
                }
            }
        }
    }
}

// ---------------- flash attention: 2-wave blocks, head-on-x XCD locality --
// grid (32 heads, 32 qtiles). block 128 = 2 waves, each wave 32 q-rows.
// flat id % 8 == head % 8 -> all q-blocks of a head on one XCD; 4 heads
// x 1MB K/V = 4MB = L2. KV tiles 64, double-buffered gload_lds + swizzle.
__global__ __launch_bounds__(128) void attn_kernel(
    const unsigned short* __restrict__ Qh, const unsigned short* __restrict__ Kh,
    const unsigned short* __restrict__ VT, float* __restrict__ out)
{
    __shared__ unsigned char Ksm[2][8192];   // [64 keys][128B d], swizzled
    __shared__ unsigned char Vsm[2][8192];   // [64 d][128B keys], swizzled

    const int tid  = threadIdx.x;
    const int wave = tid >> 6;
    const int lane = tid & 63;
    const int c    = lane & 31;
    const int hi   = lane >> 5;
    const int bh   = blockIdx.x;             // head on x: XCD = head % 8
    const int q0w  = blockIdx.y * 64 + wave * 32;
    const int sw   = (c & 7) << 4;           // read-side XOR swizzle

    const unsigned short* Qb = Qh + (size_t)bh * NSEQ * HDIM;
    const char* Kb = (const char*)(Kh + (size_t)bh * NSEQ * HDIM);
    const char* Vb = (const char*)(VT + (size_t)bh * HDIM * NSEQ);

    // Q as B-operand: lane holds Q[d = 16s+8hi+j][q = q0w+c] (pre-scaled)
    bf16x8 qf[4];
    #pragma unroll
    for (int s = 0; s < 4; s++)
        qf[s] = *reinterpret_cast<const bf16x8*>(
            Qb + (size_t)(q0w + c) * HDIM + s * 16 + hi * 8);

    const f32x16 z16 = {0,0,0,0,0,0,0,0,0,0,0,0,0,0,0,0};
    f32x16 o0 = z16, o1 = z16;
    float mrun = -1e30f, lrun = 0.f;

    // staging: 8 chunks of 1KB per buffer; wave w covers chunks i*2+w
    const int sr7 = lane >> 3;
    const int scb = ((lane & 7) * 16) ^ (sr7 << 4);   // pre-swizzled source

    auto stage = [&](int buf, int n0) {
        #pragma unroll
        for (int i = 0; i < 4; ++i) {
            const int ch  = i * 2 + wave;
            const int row = ch * 8 + sr7;
            gload16(Kb + (size_t)(n0 + row) * 128 + scb, &Ksm[buf][ch * 1024]);
            gload16(Vb + (size_t)row * (NSEQ * 2) + (size_t)n0 * 2 + scb,
                    &Vsm[buf][ch * 1024]);
        }
    };

    stage(0, 0);
    __syncthreads();
    int cur = 0;

    for (int t = 0; t < 32; ++t) {
        if (t < 31) stage(cur ^ 1, (t + 1) * 64);

        // S^T tiles: s0 = keys 0..31, s1 = keys 32..63 (cols = q)
        f32x16 s0 = z16, s1 = z16;
        __builtin_amdgcn_s_setprio(1);
        #pragma unroll
        for (int s = 0; s < 4; s++) {
            const int cb = (32 * s + 16 * hi) ^ sw;
            bf16x8 kf0 = *reinterpret_cast<const bf16x8*>(&Ksm[cur][c * 128 + cb]);
            bf16x8 kf1 = *reinterpret_cast<const bf16x8*>(&Ksm[cur][(32 + c) * 128 + cb]);
            s0 = __builtin_amdgcn_mfma_f32_32x32x16_bf16(kf0, qf[s], s0, 0, 0, 0);
            s1 = __builtin_amdgcn_mfma_f32_32x32x16_bf16(kf1, qf[s], s1, 0, 0, 0);
        }
        __builtin_amdgcn_s_setprio(0);

        // row max: 31 in-lane + 1 partner exchange (lane^32 holds other keys)
        float tmx[8];
        #pragma unroll
        for (int i = 0; i < 8; i++)
            tmx[i] = fmaxf(fmaxf(s0[2 * i], s0[2 * i + 1]),
                           fmaxf(s1[2 * i], s1[2 * i + 1]));
        float tm = fmaxf(fmaxf(fmaxf(tmx[0], tmx[1]), fmaxf(tmx[2], tmx[3])),
                         fmaxf(fmaxf(tmx[4], tmx[5]), fmaxf(tmx[6], tmx[7])));
        tm = fmaxf(tm, __shfl_xor(tm, 32));

        // defer-max: rescale only when a row max grew past threshold
        if (!__all(tm - mrun <= DEFER_THR)) {
            const float mnew  = fmaxf(mrun, tm);
            const float alpha = exp2f(mrun - mnew);
            mrun = mnew;
            lrun *= alpha;
            #pragma unroll
            for (int r = 0; r < 16; r++) {
                const float ar = __shfl(alpha, (r & 3) + 8 * (r >> 2) + 4 * hi);
                o0[r] *= ar;
                o1[r] *= ar;
            }
        }

        // P = exp2(S - m), row sum
        #pragma unroll
        for (int r = 0; r < 16; r++) s0[r] = exp2f(s0[r] - mrun);
        #pragma unroll
        for (int r = 0; r < 16; r++) s1[r] = exp2f(s1[r] - mrun);
        float rsx[8];
        #pragma unroll
        for (int i = 0; i < 8; i++)
            rsx[i] = (s0[2 * i] + s0[2 * i + 1]) + (s1[2 * i] + s1[2 * i + 1]);
        float rs = ((rsx[0] + rsx[1]) + (rsx[2] + rsx[3])) +
                   ((rsx[4] + rsx[5]) + (rsx[6] + rsx[7]));
        rs += __shfl_xor(rs, 32);
        lrun += rs;

        // P -> A-fragments in-register: cvt_pk pairs + permlane32_swap
        unsigned pw[4][4];
        #pragma unroll
        for (int u = 0; u < 4; u++) {
            const f32x16& sv = (u < 2) ? s0 : s1;
            const int b = (u & 1) * 8;
            unsigned x0 = pkbf(sv[b + 0], sv[b + 1]);
            unsigned y0 = pkbf(sv[b + 4], sv[b + 5]);
            asm("v_permlane32_swap_b32 %0, %1" : "+v"(x0), "+v"(y0));
            unsigned x1 = pkbf(sv[b + 2], sv[b + 3]);
            unsigned y1 = pkbf(sv[b + 6], sv[b + 7]);
            asm("v_permlane32_swap_b32 %0, %1" : "+v"(x1), "+v"(y1));
            pw[u][0] = x0; pw[u][1] = x1; pw[u][2] = y0; pw[u][3] = y1;
        }

        // O += P V  (o0: d 0..31, o1: d 32..63)
        __builtin_amdgcn_s_setprio(1);
        #pragma unroll
        for (int u = 0; u < 4; u++) {
            uint4 w;
            w.x = pw[u][0]; w.y = pw[u][1]; w.z = pw[u][2]; w.w = pw[u][3];
            bf16x8 pa = __builtin_bit_cast(bf16x8, w);
            const int cb = (32 * u + 16 * hi) ^ sw;
            bf16x8 vf0 = *reinterpret_cast<const bf16x8*>(&Vsm[cur][c * 128 + cb]);
            bf16x8 vf1 = *reinterpret_cast<const bf16x8*>(&Vsm[cur][(32 + c) * 128 + cb]);
            o0 = __builtin_amdgcn_mfma_f32_32x32x16_bf16(pa, vf0, o0, 0, 0, 0);
            o1 = __builtin_amdgcn_mfma_f32_32x32x16_bf16(pa, vf1, o1, 0, 0, 0);
        }
        __builtin_amdgcn_s_setprio(0);

        __syncthreads();
        cur ^= 1;
    }

    // epilogue: normalize rows, write [B,N,C] f32
    const int b = bh >> 4, h = bh & 15;
    #pragma unroll
    for (int r = 0; r < 16; r++) {
        const int qrow = (r & 3) + 8 * (r >> 2) + 4 * hi;
        const float li  = __shfl(lrun, qrow);
        const float inv = 1.0f / li;
        const int n = q0w + qrow;
        float* op = out + ((size_t)(b * NSEQ + n) << 10) + h * HDIM + c;
        op[0]  = o0[r] * inv;
        op[32] = o1[r] * inv;
    }
}

extern "C" void kernel_launch(void* const* d_in, const int* in_sizes, int n_in,
                              void* d_out, int out_size, void* d_ws, size_t ws_size,
                              hipStream_t stream) {
    const float* q    = (const float*)d_in[0];
    const float* k    = (const float*)d_in[1];
    const float* v    = (const float*)d_in[2];
    const float* qcos = (const float*)d_in[3];
    const float* qsin = (const float*)d_in[4];
    const float* kcos = (const float*)d_in[5];
    const float* ksin = (const float*)d_in[6];
    const float* Wq   = (const float*)d_in[7];
    const float* bq   = (const float*)d_in[8];
    const float* Wk   = (const float*)d_in[9];
    const float* bk   = (const float*)d_in[10];
    const float* Wv   = (const float*)d_in[11];
    const float* bv   = (const float*)d_in[12];
    float* out = (float*)d_out;

    unsigned short* Xqb = (unsigned short*)d_ws;
    unsigned short* Xkb = Xqb + (size_t)MROWS * CDIM;
    unsigned short* Xvb = Xkb + (size_t)MROWS * CDIM;
    unsigned short* Wqb = Xvb + (size_t)MROWS * CDIM;
    unsigned short* Wkb = Wqb + (size_t)CDIM * CDIM;
    unsigned short* Wvb = Wkb + (size_t)CDIM * CDIM;
    unsigned short* Qhb = Wvb + (size_t)CDIM * CDIM;
    unsigned short* Khb = Qhb + (size_t)MROWS * CDIM;
    unsigned short* VTb = Khb + (size_t)MROWS * CDIM;

    cvt6_kernel<<<15360, 256, 0, stream>>>(q, k, v, Wq, Wk, Wv,
                                           Xqb, Xkb, Xvb, Wqb, Wkb, Wvb);

    dim3 gg(CDIM / 128, MROWS / 128, 3);
    gemm_rope_kernel<<<gg, 256, 0, stream>>>(Xqb, Xkb, Xvb, Wqb, Wkb, Wvb,
                                             bq, bk, bv, qcos, qsin, kcos, ksin,
                                             Qhb, Khb, VTb);

    attn_kernel<<<dim3(2 * NHEAD, NSEQ / 64), 128, 0, stream>>>(Qhb, Khb, VTb, out);
}

// Round 7
// 143.445 us; speedup vs baseline: 1.2092x; 1.0010x over previous
//
#include <hip/hip_runtime.h>
#include <hip/hip_bf16.h>

typedef float f32x4 __attribute__((ext_vector_type(4)));
typedef float f32x16 __attribute__((ext_vector_type(16)));
typedef short bf16x8 __attribute__((ext_vector_type(8)));

#define NSEQ 2048
#define CDIM 1024
#define NHEAD 16
#define HDIM 64
#define MROWS 4096
// scale(1/8) * log2(e) folded into Q at projection epilogue
#define QSCALE 0.18033688011f
// defer-max threshold: 8 / ln(2) (P bounded by e^8)
#define DEFER_THR 11.5416f

__device__ __forceinline__ unsigned short f2bf(float f) {
    unsigned int u = __builtin_bit_cast(unsigned int, f);
    u += 0x7FFFu + ((u >> 16) & 1u);
    return (unsigned short)(u >> 16);
}

__device__ __forceinline__ unsigned pkbf(float lo, float hi_) {
    unsigned r;
    asm("v_cvt_pk_bf16_f32 %0, %1, %2" : "=v"(r) : "v"(lo), "v"(hi_));
    return r;
}

__device__ __forceinline__ void gload16(const void* g, void* l) {
    __builtin_amdgcn_global_load_lds(
        (const __attribute__((address_space(1))) unsigned int*)g,
        (__attribute__((address_space(3))) unsigned int*)l, 16, 0, 0);
}

// ---------------- all f32->bf16 conversions in ONE launch ----------------
__global__ __launch_bounds__(256) void cvt6_kernel(
    const float* __restrict__ q, const float* __restrict__ k, const float* __restrict__ v,
    const float* __restrict__ wq, const float* __restrict__ wk, const float* __restrict__ wv,
    unsigned short* __restrict__ dq, unsigned short* __restrict__ dk, unsigned short* __restrict__ dv,
    unsigned short* __restrict__ dwq, unsigned short* __restrict__ dwk, unsigned short* __restrict__ dwv)
{
    int b = blockIdx.x;
    const float* s; unsigned short* d; int base;
    if (b < 4096)       { s = q;  d = dq;  base = b; }
    else if (b < 8192)  { s = k;  d = dk;  base = b - 4096; }
    else if (b < 12288) { s = v;  d = dv;  base = b - 8192; }
    else if (b < 13312) { s = wq; d = dwq; base = b - 12288; }
    else if (b < 14336) { s = wk; d = dwk; base = b - 13312; }
    else                { s = wv; d = dwv; base = b - 14336; }
    int i = (base * 256 + threadIdx.x) * 4;
    float4 t4 = *reinterpret_cast<const float4*>(s + i);
    ushort4 o;
    o.x = f2bf(t4.x); o.y = f2bf(t4.y); o.z = f2bf(t4.z); o.w = f2bf(t4.w);
    *reinterpret_cast<ushort4*>(d + i) = o;
}

// ---------------- fused projection GEMM + bias + RoPE -------------------
// round-3 structure: padded LDS [128][72], bf16x8 VALU staging (best measured)
__global__ __launch_bounds__(256) void gemm_rope_kernel(
    const unsigned short* __restrict__ Xq, const unsigned short* __restrict__ Xk,
    const unsigned short* __restrict__ Xv,
    const unsigned short* __restrict__ Wqb, const unsigned short* __restrict__ Wkb,
    const unsigned short* __restrict__ Wvb,
    const float* __restrict__ bq, const float* __restrict__ bk, const float* __restrict__ bv,
    const float* __restrict__ qcos, const float* __restrict__ qsin,
    const float* __restrict__ kcos, const float* __restrict__ ksin,
    unsigned short* __restrict__ Qh, unsigned short* __restrict__ Kh,
    unsigned short* __restrict__ VT)
{
    __shared__ unsigned short Al[128][72];
    __shared__ unsigned short Bl[128][72];

    const int tid  = threadIdx.x;
    const int wave = tid >> 6;
    const int lane = tid & 63;
    const int lr   = lane & 15;
    const int lg   = lane >> 4;
    const int lk   = lg * 8;
    const int wm   = wave >> 1;
    const int wn   = wave & 1;
    const int m0   = blockIdx.y * 128;
    const int j0   = blockIdx.x * 128;
    const int z    = blockIdx.z;

    const unsigned short* X = (z == 0) ? Xq : (z == 1) ? Xk : Xv;
    const unsigned short* W = (z == 0) ? Wqb : (z == 1) ? Wkb : Wvb;
    const float* bias = (z == 0) ? bq : (z == 1) ? bk : bv;
    const float* cosb = (z == 0) ? qcos : kcos;
    const float* sinb = (z == 0) ? qsin : ksin;

    f32x4 acc[4][4];
    const f32x4 zero4 = {0.f, 0.f, 0.f, 0.f};
    #pragma unroll
    for (int a = 0; a < 4; a++)
        #pragma unroll
        for (int b = 0; b < 4; b++) acc[a][b] = zero4;

    for (int k0 = 0; k0 < CDIM; k0 += 64) {
        __syncthreads();
        #pragma unroll
        for (int it = 0; it < 4; it++) {
            int c = tid + it * 256;
            int row = c >> 3, col = (c & 7) << 3;
            *reinterpret_cast<bf16x8*>(&Al[row][col]) =
                *reinterpret_cast<const bf16x8*>(X + (size_t)(m0 + row) * CDIM + k0 + col);
            *reinterpret_cast<bf16x8*>(&Bl[row][col]) =
                *reinterpret_cast<const bf16x8*>(W + (size_t)(j0 + row) * CDIM + k0 + col);
        }
        __syncthreads();
        #pragma unroll
        for (int ks = 0; ks < 2; ks++) {
            bf16x8 af[4], bfm[4];
            #pragma unroll
            for (int mi = 0; mi < 4; mi++)
                af[mi] = *reinterpret_cast<const bf16x8*>(&Al[wm * 64 + 16 * mi + lr][ks * 32 + lk]);
            #pragma unroll
            for (int ni = 0; ni < 4; ni++)
                bfm[ni] = *reinterpret_cast<const bf16x8*>(&Bl[wn * 64 + 16 * ni + lr][ks * 32 + lk]);
            #pragma unroll
            for (int mi = 0; mi < 4; mi++)
                #pragma unroll
                for (int ni = 0; ni < 4; ni++)
                    acc[mi][ni] = __builtin_amdgcn_mfma_f32_16x16x32_bf16(
                        af[mi], bfm[ni], acc[mi][ni], 0, 0, 0);
        }
    }

    #pragma unroll
    for (int mi = 0; mi < 4; mi++) {
        const int mbase = m0 + wm * 64 + 16 * mi + 4 * lg;
        #pragma unroll
        for (int ni = 0; ni < 4; ni++) {
            const int j  = j0 + wn * 64 + 16 * ni + lr;
            const float bj = bias[j];
            if (z == 2) {
                const int b = mbase >> 11, n = mbase & 2047;
                const int h = j >> 6, d = j & 63;
                ushort4 pk;
                pk.x = f2bf(acc[mi][ni][0] + bj);
                pk.y = f2bf(acc[mi][ni][1] + bj);
                pk.z = f2bf(acc[mi][ni][2] + bj);
                pk.w = f2bf(acc[mi][ni][3] + bj);
                *reinterpret_cast<ushort4*>(VT + ((size_t)((b * NHEAD + h) * HDIM + d) << 11) + n) = pk;
            } else {
                unsigned short* Out = (z == 0) ? Qh : Kh;
                const float scl = (z == 0) ? QSCALE : 1.0f;
                const int hi = (j & 63) >> 1;
                const float sg = (j & 1) ? 1.f : -1.f;
                float vv[4], pp[4];
                #pragma unroll
                for (int r = 0; r < 4; r++) vv[r] = acc[mi][ni][r] + bj;
                #pragma unroll
                for (int r = 0; r < 4; r++) pp[r] = __shfl_xor(vv[r], 1);
                #pragma unroll
                for (int r = 0; r < 4; r++) {
                    const int m = mbase + r;
                    const int b = m >> 11, n = m & 2047;
                    const float c = cosb[n * 32 + hi];
                    const float s = sinb[n * 32 + hi];
                    const float ov = fmaf(vv[r], c, pp[r] * (sg * s)) * scl;
                    Out[((size_t)((b * NHEAD + (j >> 6)) * NSEQ + n) << 6) + (j & 63)] = f2bf(ov);
                }
            }
        }
    }
}

// ---------------- flash attention, KV-split x2 (flash-decoding) ----------
// grid (32 heads, 16 qtiles, 2 halves). block 256 = 4 waves x 32 q-rows.
// Each block covers keys [half*1024, +1024) = 16 tiles of 64; writes
// UNNORMALIZED partial O (half0 -> out buffer, half1 -> scratch) + (m,l).
__global__ __launch_bounds__(256, 2) void attn_kernel(
    const unsigned short* __restrict__ Qh, const unsigned short* __restrict__ Kh,
    const unsigned short* __restrict__ VT, float* __restrict__ out,
    float* __restrict__ O2, float2* __restrict__ ML)
{
    __shared__ unsigned char Ksm[2][8192];   // [64 keys][128B d], swizzled
    __shared__ unsigned char Vsm[2][8192];   // [64 d][128B keys], swizzled

    const int tid  = threadIdx.x;
    const int wave = tid >> 6;
    const int lane = tid & 63;
    const int c    = lane & 31;
    const int hi   = lane >> 5;
    const int bh   = blockIdx.x;             // head on x: XCD = head % 8
    const int q0w  = blockIdx.y * 128 + wave * 32;
    const int half = blockIdx.z;
    const int kbase = half * 1024;
    const int sw   = (c & 7) << 4;           // read-side XOR swizzle

    const unsigned short* Qb = Qh + (size_t)bh * NSEQ * HDIM;
    const char* Kb = (const char*)(Kh + (size_t)bh * NSEQ * HDIM);
    const char* Vb = (const char*)(VT + (size_t)bh * HDIM * NSEQ);

    // Q as B-operand: lane holds Q[d = 16s+8hi+j][q = q0w+c] (pre-scaled)
    bf16x8 qf[4];
    #pragma unroll
    for (int s = 0; s < 4; s++)
        qf[s] = *reinterpret_cast<const bf16x8*>(
            Qb + (size_t)(q0w + c) * HDIM + s * 16 + hi * 8);

    const f32x16 z16 = {0,0,0,0,0,0,0,0,0,0,0,0,0,0,0,0};
    f32x16 o0 = z16, o1 = z16;
    float mrun = -1e30f, lrun = 0.f;

    // staging: thread stages 2x16B of K and V each (pre-swizzled source)
    const int sr7 = lane >> 3;
    const int scb = ((lane & 7) * 16) ^ (sr7 << 4);
    const int ch0 = wave * 2;

    auto stage = [&](int buf, int n0) {
        #pragma unroll
        for (int i = 0; i < 2; ++i) {
            const int row = (ch0 + i) * 8 + sr7;
            gload16(Kb + (size_t)(n0 + row) * 128 + scb, &Ksm[buf][(ch0 + i) * 1024]);
            gload16(Vb + (size_t)row * (NSEQ * 2) + (size_t)n0 * 2 + scb,
                    &Vsm[buf][(ch0 + i) * 1024]);
        }
    };

    stage(0, kbase);
    __syncthreads();
    int cur = 0;

    for (int t = 0; t < 16; ++t) {
        if (t < 15) stage(cur ^ 1, kbase + (t + 1) * 64);

        // S^T tiles: s0 = keys 0..31, s1 = keys 32..63 (cols = q)
        f32x16 s0 = z16, s1 = z16;
        __builtin_amdgcn_s_setprio(1);
        #pragma unroll
        for (int s = 0; s < 4; s++) {
            const int cb = (32 * s + 16 * hi) ^ sw;
            bf16x8 kf0 = *reinterpret_cast<const bf16x8*>(&Ksm[cur][c * 128 + cb]);
            bf16x8 kf1 = *reinterpret_cast<const bf16x8*>(&Ksm[cur][(32 + c) * 128 + cb]);
            s0 = __builtin_amdgcn_mfma_f32_32x32x16_bf16(kf0, qf[s], s0, 0, 0, 0);
            s1 = __builtin_amdgcn_mfma_f32_32x32x16_bf16(kf1, qf[s], s1, 0, 0, 0);
        }
        __builtin_amdgcn_s_setprio(0);

        // row max: 31 in-lane + 1 partner exchange (lane^32 holds other keys)
        float tmx[8];
        #pragma unroll
        for (int i = 0; i < 8; i++)
            tmx[i] = fmaxf(fmaxf(s0[2 * i], s0[2 * i + 1]),
                           fmaxf(s1[2 * i], s1[2 * i + 1]));
        float tm = fmaxf(fmaxf(fmaxf(tmx[0], tmx[1]), fmaxf(tmx[2], tmx[3])),
                         fmaxf(fmaxf(tmx[4], tmx[5]), fmaxf(tmx[6], tmx[7])));
        tm = fmaxf(tm, __shfl_xor(tm, 32));

        // defer-max: rescale only when a row max grew past threshold
        if (!__all(tm - mrun <= DEFER_THR)) {
            const float mnew  = fmaxf(mrun, tm);
            const float alpha = exp2f(mrun - mnew);
            mrun = mnew;
            lrun *= alpha;
            #pragma unroll
            for (int r = 0; r < 16; r++) {
                const float ar = __shfl(alpha, (r & 3) + 8 * (r >> 2) + 4 * hi);
                o0[r] *= ar;
                o1[r] *= ar;
            }
        }

        // P = exp2(S - m), row sum
        #pragma unroll
        for (int r = 0; r < 16; r++) s0[r] = exp2f(s0[r] - mrun);
        #pragma unroll
        for (int r = 0; r < 16; r++) s1[r] = exp2f(s1[r] - mrun);
        float rsx[8];
        #pragma unroll
        for (int i = 0; i < 8; i++)
            rsx[i] = (s0[2 * i] + s0[2 * i + 1]) + (s1[2 * i] + s1[2 * i + 1]);
        float rs = ((rsx[0] + rsx[1]) + (rsx[2] + rsx[3])) +
                   ((rsx[4] + rsx[5]) + (rsx[6] + rsx[7]));
        rs += __shfl_xor(rs, 32);
        lrun += rs;

        // P -> A-fragments in-register: cvt_pk pairs + permlane32_swap
        unsigned pw[4][4];
        #pragma unroll
        for (int u = 0; u < 4; u++) {
            const f32x16& sv = (u < 2) ? s0 : s1;
            const int b = (u & 1) * 8;
            unsigned x0 = pkbf(sv[b + 0], sv[b + 1]);
            unsigned y0 = pkbf(sv[b + 4], sv[b + 5]);
            asm("v_permlane32_swap_b32 %0, %1" : "+v"(x0), "+v"(y0));
            unsigned x1 = pkbf(sv[b + 2], sv[b + 3]);
            unsigned y1 = pkbf(sv[b + 6], sv[b + 7]);
            asm("v_permlane32_swap_b32 %0, %1" : "+v"(x1), "+v"(y1));
            pw[u][0] = x0; pw[u][1] = x1; pw[u][2] = y0; pw[u][3] = y1;
        }

        // O += P V  (o0: d 0..31, o1: d 32..63)
        __builtin_amdgcn_s_setprio(1);
        #pragma unroll
        for (int u = 0; u < 4; u++) {
            uint4 w;
            w.x = pw[u][0]; w.y = pw[u][1]; w.z = pw[u][2]; w.w = pw[u][3];
            bf16x8 pa = __builtin_bit_cast(bf16x8, w);
            const int cb = (32 * u + 16 * hi) ^ sw;
            bf16x8 vf0 = *reinterpret_cast<const bf16x8*>(&Vsm[cur][c * 128 + cb]);
            bf16x8 vf1 = *reinterpret_cast<const bf16x8*>(&Vsm[cur][(32 + c) * 128 + cb]);
            o0 = __builtin_amdgcn_mfma_f32_32x32x16_bf16(pa, vf0, o0, 0, 0, 0);
            o1 = __builtin_amdgcn_mfma_f32_32x32x16_bf16(pa, vf1, o1, 0, 0, 0);
        }
        __builtin_amdgcn_s_setprio(0);

        __syncthreads();
        cur ^= 1;
    }

    // epilogue: write UNNORMALIZED partial O + per-row (m,l)
    float* obase = half ? O2 : out;
    const int b = bh >> 4, h = bh & 15;
    #pragma unroll
    for (int r = 0; r < 16; r++) {
        const int qrow = (r & 3) + 8 * (r >> 2) + 4 * hi;
        const int n = q0w + qrow;
        float* op = obase + ((size_t)(b * NSEQ + n) << 10) + h * HDIM + c;
        op[0]  = o0[r];
        op[32] = o1[r];
    }
    if (hi == 0)
        ML[((size_t)half * 32 + bh) * NSEQ + q0w + c] = make_float2(mrun, lrun);
}

// ---------------- combine the two KV halves (memory-bound) ---------------
__global__ __launch_bounds__(256) void attn_combine(
    float* __restrict__ out, const float* __restrict__ O2,
    const float2* __restrict__ ML)
{
    const int idx4 = blockIdx.x * 256 + threadIdx.x;   // float4 index
    const int e    = idx4 * 4;
    const int row  = e >> 10;          // b*2048+n
    const int col  = e & 1023;
    const int h    = col >> 6;
    const int b    = row >> 11;
    const int n    = row & 2047;
    const int bh   = b * NHEAD + h;

    const float2 ml1 = ML[(size_t)bh * NSEQ + n];
    const float2 ml2 = ML[((size_t)32 + bh) * NSEQ + n];
    const float M  = fmaxf(ml1.x, ml2.x);
    const float w1 = exp2f(ml1.x - M);
    const float w2 = exp2f(ml2.x - M);
    const float inv = 1.0f / (w1 * ml1.y + w2 * ml2.y);

    float4 a = reinterpret_cast<float4*>(out)[idx4];
    float4 d = reinterpret_cast<const float4*>(O2)[idx4];
    float4 r;
    r.x = (w1 * a.x + w2 * d.x) * inv;
    r.y = (w1 * a.y + w2 * d.y) * inv;
    r.z = (w1 * a.z + w2 * d.z) * inv;
    r.w = (w1 * a.w + w2 * d.w) * inv;
    reinterpret_cast<float4*>(out)[idx4] = r;
}

extern "C" void kernel_launch(void* const* d_in, const int* in_sizes, int n_in,
                              void* d_out, int out_size, void* d_ws, size_t ws_size,
                              hipStream_t stream) {
    const float* q    = (const float*)d_in[0];
    const float* k    = (const float*)d_in[1];
    const float* v    = (const float*)d_in[2];
    const float* qcos = (const float*)d_in[3];
    const float* qsin = (const float*)d_in[4];
    const float* kcos = (const float*)d_in[5];
    const float* ksin = (const float*)d_in[6];
    const float* Wq   = (const float*)d_in[7];
    const float* bq   = (const float*)d_in[8];
    const float* Wk   = (const float*)d_in[9];
    const float* bk   = (const float*)d_in[10];
    const float* Wv   = (const float*)d_in[11];
    const float* bv   = (const float*)d_in[12];
    float* out = (float*)d_out;

    unsigned short* Xqb = (unsigned short*)d_ws;
    unsigned short* Xkb = Xqb + (size_t)MROWS * CDIM;
    unsigned short* Xvb = Xkb + (size_t)MROWS * CDIM;
    unsigned short* Wqb = Xvb + (size_t)MROWS * CDIM;
    unsigned short* Wkb = Wqb + (size_t)CDIM * CDIM;
    unsigned short* Wvb = Wkb + (size_t)CDIM * CDIM;
    unsigned short* Qhb = Wvb + (size_t)CDIM * CDIM;
    unsigned short* Khb = Qhb + (size_t)MROWS * CDIM;
    unsigned short* VTb = Khb + (size_t)MROWS * CDIM;

    // dead-after-gemm region reuse: O2 (16MB) over Xqb/Xkb, ML (1MB) in Xvb
    float*  O2 = (float*)Xqb;
    float2* ML = (float2*)((char*)d_ws + (size_t)16 * 1024 * 1024);

    cvt6_kernel<<<15360, 256, 0, stream>>>(q, k, v, Wq, Wk, Wv,
                                           Xqb, Xkb, Xvb, Wqb, Wkb, Wvb);

    dim3 gg(CDIM / 128, MROWS / 128, 3);
    gemm_rope_kernel<<<gg, 256, 0, stream>>>(Xqb, Xkb, Xvb, Wqb, Wkb, Wvb,
                                             bq, bk, bv, qcos, qsin, kcos, ksin,
                                             Qhb, Khb, VTb);

    attn_kernel<<<dim3(2 * NHEAD, NSEQ / 128, 2), 256, 0, stream>>>(
        Qhb, Khb, VTb, out, O2, ML);

    attn_combine<<<(MROWS * CDIM / 4) / 256, 256, 0, stream>>>(out, O2, ML);
}

// Round 8
// 140.398 us; speedup vs baseline: 1.2355x; 1.0217x over previous
//
#include <hip/hip_runtime.h>
#include <hip/hip_bf16.h>

typedef float f32x4 __attribute__((ext_vector_type(4)));
typedef float f32x16 __attribute__((ext_vector_type(16)));
typedef short bf16x8 __attribute__((ext_vector_type(8)));

#define NSEQ 2048
#define CDIM 1024
#define NHEAD 16
#define HDIM 64
#define MROWS 4096
// scale(1/8) * log2(e) folded into Q at projection epilogue
#define QSCALE 0.18033688011f
// defer-max threshold: 8 / ln(2) (P bounded by e^8)
#define DEFER_THR 11.5416f

__device__ __forceinline__ unsigned short f2bf(float f) {
    unsigned int u = __builtin_bit_cast(unsigned int, f);
    u += 0x7FFFu + ((u >> 16) & 1u);
    return (unsigned short)(u >> 16);
}

__device__ __forceinline__ unsigned pkbf(float lo, float hi_) {
    unsigned r;
    asm("v_cvt_pk_bf16_f32 %0, %1, %2" : "=v"(r) : "v"(lo), "v"(hi_));
    return r;
}

__device__ __forceinline__ void gload16(const void* g, void* l) {
    __builtin_amdgcn_global_load_lds(
        (const __attribute__((address_space(1))) unsigned int*)g,
        (__attribute__((address_space(3))) unsigned int*)l, 16, 0, 0);
}

// ---------------- all f32->bf16 conversions in ONE launch ----------------
__global__ __launch_bounds__(256) void cvt6_kernel(
    const float* __restrict__ q, const float* __restrict__ k, const float* __restrict__ v,
    const float* __restrict__ wq, const float* __restrict__ wk, const float* __restrict__ wv,
    unsigned short* __restrict__ dq, unsigned short* __restrict__ dk, unsigned short* __restrict__ dv,
    unsigned short* __restrict__ dwq, unsigned short* __restrict__ dwk, unsigned short* __restrict__ dwv)
{
    int b = blockIdx.x;
    const float* s; unsigned short* d; int base;
    if (b < 4096)       { s = q;  d = dq;  base = b; }
    else if (b < 8192)  { s = k;  d = dk;  base = b - 4096; }
    else if (b < 12288) { s = v;  d = dv;  base = b - 8192; }
    else if (b < 13312) { s = wq; d = dwq; base = b - 12288; }
    else if (b < 14336) { s = wk; d = dwk; base = b - 13312; }
    else                { s = wv; d = dwv; base = b - 14336; }
    int i = (base * 256 + threadIdx.x) * 4;
    float4 t4 = *reinterpret_cast<const float4*>(s + i);
    ushort4 o;
    o.x = f2bf(t4.x); o.y = f2bf(t4.y); o.z = f2bf(t4.z); o.w = f2bf(t4.w);
    *reinterpret_cast<ushort4*>(d + i) = o;
}

// ---------------- fused projection GEMM + bias + RoPE -------------------
// round-3 structure: padded LDS [128][72], bf16x8 VALU staging (best measured)
__global__ __launch_bounds__(256) void gemm_rope_kernel(
    const unsigned short* __restrict__ Xq, const unsigned short* __restrict__ Xk,
    const unsigned short* __restrict__ Xv,
    const unsigned short* __restrict__ Wqb, const unsigned short* __restrict__ Wkb,
    const unsigned short* __restrict__ Wvb,
    const float* __restrict__ bq, const float* __restrict__ bk, const float* __restrict__ bv,
    const float* __restrict__ qcos, const float* __restrict__ qsin,
    const float* __restrict__ kcos, const float* __restrict__ ksin,
    unsigned short* __restrict__ Qh, unsigned short* __restrict__ Kh,
    unsigned short* __restrict__ VT)
{
    __shared__ unsigned short Al[128][72];
    __shared__ unsigned short Bl[128][72];

    const int tid  = threadIdx.x;
    const int wave = tid >> 6;
    const int lane = tid & 63;
    const int lr   = lane & 15;
    const int lg   = lane >> 4;
    const int lk   = lg * 8;
    const int wm   = wave >> 1;
    const int wn   = wave & 1;
    const int m0   = blockIdx.y * 128;
    const int j0   = blockIdx.x * 128;
    const int z    = blockIdx.z;

    const unsigned short* X = (z == 0) ? Xq : (z == 1) ? Xk : Xv;
    const unsigned short* W = (z == 0) ? Wqb : (z == 1) ? Wkb : Wvb;
    const float* bias = (z == 0) ? bq : (z == 1) ? bk : bv;
    const float* cosb = (z == 0) ? qcos : kcos;
    const float* sinb = (z == 0) ? qsin : ksin;

    f32x4 acc[4][4];
    const f32x4 zero4 = {0.f, 0.f, 0.f, 0.f};
    #pragma unroll
    for (int a = 0; a < 4; a++)
        #pragma unroll
        for (int b = 0; b < 4; b++) acc[a][b] = zero4;

    for (int k0 = 0; k0 < CDIM; k0 += 64) {
        __syncthreads();
        #pragma unroll
        for (int it = 0; it < 4; it++) {
            int c = tid + it * 256;
            int row = c >> 3, col = (c & 7) << 3;
            *reinterpret_cast<bf16x8*>(&Al[row][col]) =
                *reinterpret_cast<const bf16x8*>(X + (size_t)(m0 + row) * CDIM + k0 + col);
            *reinterpret_cast<bf16x8*>(&Bl[row][col]) =
                *reinterpret_cast<const bf16x8*>(W + (size_t)(j0 + row) * CDIM + k0 + col);
        }
        __syncthreads();
        #pragma unroll
        for (int ks = 0; ks < 2; ks++) {
            bf16x8 af[4], bfm[4];
            #pragma unroll
            for (int mi = 0; mi < 4; mi++)
                af[mi] = *reinterpret_cast<const bf16x8*>(&Al[wm * 64 + 16 * mi + lr][ks * 32 + lk]);
            #pragma unroll
            for (int ni = 0; ni < 4; ni++)
                bfm[ni] = *reinterpret_cast<const bf16x8*>(&Bl[wn * 64 + 16 * ni + lr][ks * 32 + lk]);
            #pragma unroll
            for (int mi = 0; mi < 4; mi++)
                #pragma unroll
                for (int ni = 0; ni < 4; ni++)
                    acc[mi][ni] = __builtin_amdgcn_mfma_f32_16x16x32_bf16(
                        af[mi], bfm[ni], acc[mi][ni], 0, 0, 0);
        }
    }

    #pragma unroll
    for (int mi = 0; mi < 4; mi++) {
        const int mbase = m0 + wm * 64 + 16 * mi + 4 * lg;
        #pragma unroll
        for (int ni = 0; ni < 4; ni++) {
            const int j  = j0 + wn * 64 + 16 * ni + lr;
            const float bj = bias[j];
            if (z == 2) {
                const int b = mbase >> 11, n = mbase & 2047;
                const int h = j >> 6, d = j & 63;
                ushort4 pk;
                pk.x = f2bf(acc[mi][ni][0] + bj);
                pk.y = f2bf(acc[mi][ni][1] + bj);
                pk.z = f2bf(acc[mi][ni][2] + bj);
                pk.w = f2bf(acc[mi][ni][3] + bj);
                *reinterpret_cast<ushort4*>(VT + ((size_t)((b * NHEAD + h) * HDIM + d) << 11) + n) = pk;
            } else {
                unsigned short* Out = (z == 0) ? Qh : Kh;
                const float scl = (z == 0) ? QSCALE : 1.0f;
                const int hi = (j & 63) >> 1;
                const float sg = (j & 1) ? 1.f : -1.f;
                float vv[4], pp[4];
                #pragma unroll
                for (int r = 0; r < 4; r++) vv[r] = acc[mi][ni][r] + bj;
                #pragma unroll
                for (int r = 0; r < 4; r++) pp[r] = __shfl_xor(vv[r], 1);
                #pragma unroll
                for (int r = 0; r < 4; r++) {
                    const int m = mbase + r;
                    const int b = m >> 11, n = m & 2047;
                    const float c = cosb[n * 32 + hi];
                    const float s = sinb[n * 32 + hi];
                    const float ov = fmaf(vv[r], c, pp[r] * (sg * s)) * scl;
                    Out[((size_t)((b * NHEAD + (j >> 6)) * NSEQ + n) << 6) + (j & 63)] = f2bf(ov);
                }
            }
        }
    }
}

// ---------------- flash attention, KVBLK=32, low-register ----------------
// grid (32 heads, 16 qtiles, 2 halves). block 256 = 4 waves x 32 q-rows.
// KVBLK=32 halves S/P registers (s=16, pa=8) to fit 4 waves/SIMD.
// K tile [32 keys][128B d]; V tile [32 rows][128B]: row r = d=r (bytes
// 0..63) ++ d=r+32 (bytes 64..127). Both XOR-swizzled (row&7)<<4 with
// linear gload_lds dest + pre-swizzled source (rule 21 involution).
__global__ __launch_bounds__(256, 4) void attn_kernel(
    const unsigned short* __restrict__ Qh, const unsigned short* __restrict__ Kh,
    const unsigned short* __restrict__ VT, float* __restrict__ out,
    float* __restrict__ O2, float2* __restrict__ ML)
{
    __shared__ unsigned char Ksm[2][4096];
    __shared__ unsigned char Vsm[2][4096];

    const int tid  = threadIdx.x;
    const int wave = tid >> 6;
    const int lane = tid & 63;
    const int c    = lane & 31;
    const int hi   = lane >> 5;
    const int bh   = blockIdx.x;             // head on x: XCD = head % 8
    const int q0w  = blockIdx.y * 128 + wave * 32;
    const int half = blockIdx.z;
    const int kbase = half * 1024;
    const int sw   = (c & 7) << 4;           // read-side XOR swizzle

    const unsigned short* Qb = Qh + (size_t)bh * NSEQ * HDIM;
    const char* Kb = (const char*)(Kh + (size_t)bh * NSEQ * HDIM);
    const char* Vb = (const char*)(VT + (size_t)bh * HDIM * NSEQ);

    // Q as B-operand: lane holds Q[d = 16s+8hi+j][q = q0w+c] (pre-scaled)
    bf16x8 qf[4];
    #pragma unroll
    for (int s = 0; s < 4; s++)
        qf[s] = *reinterpret_cast<const bf16x8*>(
            Qb + (size_t)(q0w + c) * HDIM + s * 16 + hi * 8);

    const f32x16 z16 = {0,0,0,0,0,0,0,0,0,0,0,0,0,0,0,0};
    f32x16 o0 = z16, o1 = z16;
    float mrun = -1e30f, lrun = 0.f;

    // staging per-thread constants: wave w stages 1KB of K + 1KB of V
    const int srow = wave * 8 + (lane >> 3);            // LDS row 0..31
    const int lb   = ((lane & 7) * 16) ^ ((srow & 7) << 4);  // logical byte
    const size_t skoff = (size_t)srow * 128 + lb;
    const int dv   = (lb & 64) ? (srow + 32) : srow;    // V d-row
    const size_t svoff = (size_t)dv * (NSEQ * 2) + (lb & 63);

    auto stage = [&](int buf, int n0) {
        gload16(Kb + (size_t)n0 * 128 + skoff, &Ksm[buf][wave * 1024]);
        gload16(Vb + (size_t)n0 * 2 + svoff, &Vsm[buf][wave * 1024]);
    };

    stage(0, kbase);
    __syncthreads();
    int cur = 0;

    for (int t = 0; t < 32; ++t) {
        if (t < 31) stage(cur ^ 1, kbase + (t + 1) * 32);

        // S^T = mfma(K, Q): lane holds S[key = crow(r,hi)][q = c], 32 keys
        f32x16 s = z16;
        __builtin_amdgcn_s_setprio(1);
        #pragma unroll
        for (int si = 0; si < 4; si++) {
            bf16x8 kf = *reinterpret_cast<const bf16x8*>(
                &Ksm[cur][c * 128 + ((si * 32 + hi * 16) ^ sw)]);
            s = __builtin_amdgcn_mfma_f32_32x32x16_bf16(kf, qf[si], s, 0, 0, 0);
        }
        __builtin_amdgcn_s_setprio(0);

        // row max: 15 in-lane + 1 partner exchange
        float tmx[8];
        #pragma unroll
        for (int i = 0; i < 8; i++) tmx[i] = fmaxf(s[2 * i], s[2 * i + 1]);
        float tm = fmaxf(fmaxf(fmaxf(tmx[0], tmx[1]), fmaxf(tmx[2], tmx[3])),
                         fmaxf(fmaxf(tmx[4], tmx[5]), fmaxf(tmx[6], tmx[7])));
        tm = fmaxf(tm, __shfl_xor(tm, 32));

        // defer-max: rescale only when a row max grew past threshold
        if (!__all(tm - mrun <= DEFER_THR)) {
            const float mnew  = fmaxf(mrun, tm);
            const float alpha = exp2f(mrun - mnew);
            mrun = mnew;
            lrun *= alpha;
            #pragma unroll
            for (int r = 0; r < 16; r++) {
                const float ar = __shfl(alpha, (r & 3) + 8 * (r >> 2) + 4 * hi);
                o0[r] *= ar;
                o1[r] *= ar;
            }
        }

        // P = exp2(S - m), row sum
        #pragma unroll
        for (int r = 0; r < 16; r++) s[r] = exp2f(s[r] - mrun);
        float rsx[8];
        #pragma unroll
        for (int i = 0; i < 8; i++) rsx[i] = s[2 * i] + s[2 * i + 1];
        float rs = ((rsx[0] + rsx[1]) + (rsx[2] + rsx[3])) +
                   ((rsx[4] + rsx[5]) + (rsx[6] + rsx[7]));
        rs += __shfl_xor(rs, 32);
        lrun += rs;

        // P -> A-fragments in-register: cvt_pk pairs + permlane32_swap
        unsigned pw[2][4];
        #pragma unroll
        for (int u = 0; u < 2; u++) {
            const int b = u * 8;
            unsigned x0 = pkbf(s[b + 0], s[b + 1]);
            unsigned y0 = pkbf(s[b + 4], s[b + 5]);
            asm("v_permlane32_swap_b32 %0, %1" : "+v"(x0), "+v"(y0));
            unsigned x1 = pkbf(s[b + 2], s[b + 3]);
            unsigned y1 = pkbf(s[b + 6], s[b + 7]);
            asm("v_permlane32_swap_b32 %0, %1" : "+v"(x1), "+v"(y1));
            pw[u][0] = x0; pw[u][1] = x1; pw[u][2] = y0; pw[u][3] = y1;
        }

        // O += P V  (o0: d 0..31, o1: d 32..63)
        __builtin_amdgcn_s_setprio(1);
        #pragma unroll
        for (int u = 0; u < 2; u++) {
            uint4 w;
            w.x = pw[u][0]; w.y = pw[u][1]; w.z = pw[u][2]; w.w = pw[u][3];
            bf16x8 pa = __builtin_bit_cast(bf16x8, w);
            bf16x8 vf0 = *reinterpret_cast<const bf16x8*>(
                &Vsm[cur][c * 128 + ((u * 32 + hi * 16) ^ sw)]);
            bf16x8 vf1 = *reinterpret_cast<const bf16x8*>(
                &Vsm[cur][c * 128 + ((64 + u * 32 + hi * 16) ^ sw)]);
            o0 = __builtin_amdgcn_mfma_f32_32x32x16_bf16(pa, vf0, o0, 0, 0, 0);
            o1 = __builtin_amdgcn_mfma_f32_32x32x16_bf16(pa, vf1, o1, 0, 0, 0);
        }
        __builtin_amdgcn_s_setprio(0);

        __syncthreads();
        cur ^= 1;
    }

    // epilogue: write UNNORMALIZED partial O + per-row (m,l)
    float* obase = half ? O2 : out;
    const int b = bh >> 4, h = bh & 15;
    #pragma unroll
    for (int r = 0; r < 16; r++) {
        const int qrow = (r & 3) + 8 * (r >> 2) + 4 * hi;
        const int n = q0w + qrow;
        float* op = obase + ((size_t)(b * NSEQ + n) << 10) + h * HDIM + c;
        op[0]  = o0[r];
        op[32] = o1[r];
    }
    if (hi == 0)
        ML[((size_t)half * 32 + bh) * NSEQ + q0w + c] = make_float2(mrun, lrun);
}

// ---------------- combine the two KV halves (memory-bound) ---------------
__global__ __launch_bounds__(256) void attn_combine(
    float* __restrict__ out, const float* __restrict__ O2,
    const float2* __restrict__ ML)
{
    const int idx4 = blockIdx.x * 256 + threadIdx.x;   // float4 index
    const int e    = idx4 * 4;
    const int row  = e >> 10;          // b*2048+n
    const int col  = e & 1023;
    const int h    = col >> 6;
    const int b    = row >> 11;
    const int n    = row & 2047;
    const int bh   = b * NHEAD + h;

    const float2 ml1 = ML[(size_t)bh * NSEQ + n];
    const float2 ml2 = ML[((size_t)32 + bh) * NSEQ + n];
    const float M  = fmaxf(ml1.x, ml2.x);
    const float w1 = exp2f(ml1.x - M);
    const float w2 = exp2f(ml2.x - M);
    const float inv = 1.0f / (w1 * ml1.y + w2 * ml2.y);

    float4 a = reinterpret_cast<float4*>(out)[idx4];
    float4 d = reinterpret_cast<const float4*>(O2)[idx4];
    float4 r;
    r.x = (w1 * a.x + w2 * d.x) * inv;
    r.y = (w1 * a.y + w2 * d.y) * inv;
    r.z = (w1 * a.z + w2 * d.z) * inv;
    r.w = (w1 * a.w + w2 * d.w) * inv;
    reinterpret_cast<float4*>(out)[idx4] = r;
}

extern "C" void kernel_launch(void* const* d_in, const int* in_sizes, int n_in,
                              void* d_out, int out_size, void* d_ws, size_t ws_size,
                              hipStream_t stream) {
    const float* q    = (const float*)d_in[0];
    const float* k    = (const float*)d_in[1];
    const float* v    = (const float*)d_in[2];
    const float* qcos = (const float*)d_in[3];
    const float* qsin = (const float*)d_in[4];
    const float* kcos = (const float*)d_in[5];
    const float* ksin = (const float*)d_in[6];
    const float* Wq   = (const float*)d_in[7];
    const float* bq   = (const float*)d_in[8];
    const float* Wk   = (const float*)d_in[9];
    const float* bk   = (const float*)d_in[10];
    const float* Wv   = (const float*)d_in[11];
    const float* bv   = (const float*)d_in[12];
    float* out = (float*)d_out;

    unsigned short* Xqb = (unsigned short*)d_ws;
    unsigned short* Xkb = Xqb + (size_t)MROWS * CDIM;
    unsigned short* Xvb = Xkb + (size_t)MROWS * CDIM;
    unsigned short* Wqb = Xvb + (size_t)MROWS * CDIM;
    unsigned short* Wkb = Wqb + (size_t)CDIM * CDIM;
    unsigned short* Wvb = Wkb + (size_t)CDIM * CDIM;
    unsigned short* Qhb = Wvb + (size_t)CDIM * CDIM;
    unsigned short* Khb = Qhb + (size_t)MROWS * CDIM;
    unsigned short* VTb = Khb + (size_t)MROWS * CDIM;

    // dead-after-gemm region reuse: O2 (16MB) over Xqb/Xkb, ML (1MB) in Xvb
    float*  O2 = (float*)Xqb;
    float2* ML = (float2*)((char*)d_ws + (size_t)16 * 1024 * 1024);

    cvt6_kernel<<<15360, 256, 0, stream>>>(q, k, v, Wq, Wk, Wv,
                                           Xqb, Xkb, Xvb, Wqb, Wkb, Wvb);

    dim3 gg(CDIM / 128, MROWS / 128, 3);
    gemm_rope_kernel<<<gg, 256, 0, stream>>>(Xqb, Xkb, Xvb, Wqb, Wkb, Wvb,
                                             bq, bk, bv, qcos, qsin, kcos, ksin,
                                             Qhb, Khb, VTb);

    attn_kernel<<<dim3(2 * NHEAD, NSEQ / 128, 2), 256, 0, stream>>>(
        Qhb, Khb, VTb, out, O2, ML);

    attn_combine<<<(MROWS * CDIM / 4) / 256, 256, 0, stream>>>(out, O2, ML);
}